// Round 2
// baseline (183.938 us; speedup 1.0000x reference)
//
#include <hip/hip_runtime.h>
#include <math.h>

#define BDIM 64
#define HDIM 512
#define WDIM 512
#define KW   31
#define PAD  15
#define INV_KK (1.0f / 961.0f)
#define TH   32                       // output rows per block (grid 64x16 = 1024 blocks)
#define NPIX ((size_t)BDIM * HDIM * WDIM)

// acc[0]: bce sum; acc[1..64]: inter[b]; acc[65..128]: union[b]
#define NACC 129

__global__ void zero_acc_kernel(double* acc) {
    int i = threadIdx.x;
    if (i < NACC) acc[i] = 0.0;
}

// ---- DPP helpers: VALU cross-lane (no LDS pipe) -------------------------
template<int CTRL, int RMASK>
__device__ __forceinline__ float dpp_add(float p) {
    int t = __builtin_amdgcn_update_dpp(0, __builtin_bit_cast(int, p),
                                        CTRL, RMASK, 0xf, true);
    return p + __builtin_bit_cast(float, t);
}

// inclusive prefix sum over 64 lanes
__device__ __forceinline__ float wave_iscan(float p) {
    p = dpp_add<0x111, 0xf>(p);   // row_shr:1
    p = dpp_add<0x112, 0xf>(p);   // row_shr:2
    p = dpp_add<0x114, 0xf>(p);   // row_shr:4
    p = dpp_add<0x118, 0xf>(p);   // row_shr:8
    p = dpp_add<0x142, 0xa>(p);   // row_bcast:15 -> rows 1,3
    p = dpp_add<0x143, 0xc>(p);   // row_bcast:31 -> rows 2,3
    return p;
}

// inclusive prefix valid through lane 31 (we only use lanes 0..29)
__device__ __forceinline__ float wave_iscan30(float p) {
    p = dpp_add<0x111, 0xf>(p);
    p = dpp_add<0x112, 0xf>(p);
    p = dpp_add<0x114, 0xf>(p);
    p = dpp_add<0x118, 0xf>(p);
    p = dpp_add<0x142, 0xa>(p);
    return p;
}

// lane i <- lane i-1 (lane 0 -> 0): inclusive->exclusive shift
__device__ __forceinline__ float wave_shr1(float p) {
    int t = __builtin_amdgcn_update_dpp(0, __builtin_bit_cast(int, p),
                                        0x138 /*WAVE_SHR1*/, 0xf, 0xf, true);
    return __builtin_bit_cast(float, t);
}

// Vertical-first separable box filter, ring-free, 2-deep software pipeline.
// One block per (image, 32-row tile). 512 threads, 8 waves; each wave owns a
// 64-column strip. Per thread: running vertical 31-row sums (vsA, vsB) for its
// two halo columns, updated by +row(t) - row(t-31) (the latter re-loaded from
// global: L2 hit). Horizontal 31-box via DPP prefix scan on emit rows only.
// All loads are unconditional (clamped addresses, validity folded into aMul/
// bMul at scan input or wave-uniform selects), issued 2 iterations (4 rows,
// >1000 cycles) ahead of use so cold-HBM latency (~900cyc) is covered.
__global__ __launch_bounds__(512, 8)
void fused_kernel(const float* __restrict__ pred,
                  const float* __restrict__ mask,
                  double* __restrict__ acc) {
    __shared__ float red[3][8];

    const int b    = blockIdx.x;
    const int y0   = blockIdx.y * TH;
    const int x    = threadIdx.x;     // output column
    const int lane = x & 63;
    const int wv   = x >> 6;
    const int s    = wv * 64;         // strip start column

    const float* mbase = mask + (size_t)b * HDIM * WDIM;
    const float* pbase = pred + (size_t)b * HDIM * WDIM;

    const int acol = s - 15 + lane;             // halo column, pos 0..63
    const int bcol = s + 49 + lane;             // halo column, pos 64..93
    // clamped addresses: loads unconditional, validity applied at scan input
    const int acolc = (acol < 0) ? 0 : ((acol > WDIM - 1) ? WDIM - 1 : acol);
    const int bcolc = (bcol > WDIM - 1) ? WDIM - 1 : bcol;
    const float aMul = (acol >= 0 && acol < WDIM) ? 1.f : 0.f;
    const float bMul = (lane < 30 && bcol < WDIM) ? 1.f : 0.f;

    const int tstart = y0 - PAD;                // first row entering the vsum
    const int tend   = y0 + TH - 1 + PAD;       // last row (62 rows total)
    const int smax   = (tstart > 0) ? tstart : 0;  // earliest legally-subtracted row

    float vsA = 0.f, vsB = 0.f;                 // vertical 31-row column sums
    float bce_acc = 0.f, inter_acc = 0.f, uni_acc = 0.f;

    // halo load: unconditional at clamped row/col; wave-uniform zero for OOB rows
    auto ld_halo = [&](int row, float& A, float& B) {
        int rc = row;
        if (rc < 0) rc = 0;
        if (rc > HDIM - 1) rc = HDIM - 1;
        const float* rp = mbase + (size_t)rc * WDIM;
        A = rp[acolc];
        B = rp[bcolc];
        if (row < 0 || row >= HDIM) { A = 0.f; B = 0.f; }
    };
    // subtracted row: rows < smax never entered the sum -> contribute 0
    auto ld_sub = [&](int row, float& S, float& T) {
        int rc = (row < smax) ? smax : row;
        const float* rp = mbase + (size_t)rc * WDIM;
        S = rp[acolc];
        T = rp[bcolc];
        if (row < smax) { S = 0.f; T = 0.f; }
    };
    // emit loads (M at output row, P at output row). Rows past the tile end are
    // prefetch-only (never consumed): clamp address, garbage is fine.
    auto ld_emit = [&](int row, float& M, float& P) {
        int rc = row - PAD;
        if (rc > HDIM - 1) rc = HDIM - 1;
        const size_t off = (size_t)rc * WDIM + x;
        M = mbase[off];
        P = pbase[off];
    };

    auto process = [&](float A, float B, float S, float T, float M, float P) {
        vsA += A - S;                       // slide vertical window
        vsB += B - T;
        float pa = wave_iscan(vsA * aMul);  // prefix over positions 0..63
        float pb = wave_iscan30(vsB * bMul);// prefix over positions 64..93
        const float atot = __builtin_bit_cast(float,
            __builtin_amdgcn_readlane(__builtin_bit_cast(int, pa), 63));
        const float v1 = __shfl(pa, (lane + 30) & 63);
        const float v2 = __shfl(pb, (lane + 30) & 63);   // = pb[lane-34] for lane>=34
        const float Phi = (lane <= 33) ? v1 : (atot + v2);
        const float Plo = wave_shr1(pa);
        const float hs  = Phi - Plo;        // full 31x31 box sum

        const float box  = hs * INV_KK;
        const float weit = 1.f + 5.f * fabsf(box - M);
        const float e1   = __expf(-fabsf(P));
        const float bce  = fmaxf(P, 0.f) - P * M + __logf(1.f + e1);
        const float rr   = __builtin_amdgcn_rcpf(1.f + e1);
        const float sp   = (P >= 0.f) ? rr : e1 * rr;    // sigmoid from e1
        bce_acc   += bce;
        inter_acc += sp * M * weit;
        uni_acc   += (sp + M) * weit;
    };

    // =====================================================================
    // Prologue: issue warmup stages AND the emit-phase prologue loads now,
    // so the emit loop's first consumes have ~15 iterations of cover.
    // =====================================================================
    const int t0 = y0 + PAD;                 // first emit-phase input row

    float wA0, wB0, wA1, wB1;                // warmup stage 0 (rows tstart, +1)
    float xA0, xB0, xA1, xB1;                // warmup stage 1 (rows tstart+2, +3)
    ld_halo(tstart,     wA0, wB0);
    ld_halo(tstart + 1, wA1, wB1);
    ld_halo(tstart + 2, xA0, xB0);
    ld_halo(tstart + 3, xA1, xB1);

    float qS0, qT0, qS1, qT1, rS0, rT0, rS1, rT1;
    float qM0, qP0, qM1, qP1, rM0, rP0, rM1, rP1;
    ld_sub (t0 - 31, qS0, qT0);              // gated to 0 unless y0>0
    ld_sub (t0 - 30, qS1, qT1);
    ld_sub (t0 - 29, rS0, rT0);
    ld_sub (t0 - 28, rS1, rT1);
    ld_emit(t0,      qM0, qP0);
    ld_emit(t0 + 1,  qM1, qP1);
    ld_emit(t0 + 2,  rM0, rP0);
    ld_emit(t0 + 3,  rM1, rP1);

    // ---- warmup: rows tstart .. y0+14 (30 rows, 15 iters), adds only ----
    // Last iterations prefetch rows y0+15..y0+18, handed to the emit loop.
#pragma unroll
    for (int i = 0; i < 15; ++i) {
        const int t = tstart + 2 * i;
        float nA0, nB0, nA1, nB1;
        ld_halo(t + 4, nA0, nB0);
        ld_halo(t + 5, nA1, nB1);
        vsA += wA0 + wA1;
        vsB += wB0 + wB1;
        wA0 = xA0; wB0 = xB0; wA1 = xA1; wB1 = xB1;
        xA0 = nA0; xB0 = nB0; xA1 = nA1; xB1 = nB1;
    }
    // wA* = rows y0+15, y0+16 ; xA* = rows y0+17, y0+18

    float qA0 = wA0, qB0 = wB0, qA1 = wA1, qB1 = wB1;
    float rA0 = xA0, rB0 = xB0, rA1 = xA1, rB1 = xB1;

    // ---- emit: rows y0+15 .. y0+46 (32 rows, 16 iters), scan + emit ----
#pragma unroll
    for (int i = 0; i < 16; ++i) {
        const int t = t0 + 2 * i;
        float nA0, nB0, nA1, nB1, nS0, nT0, nS1, nT1, nM0, nP0, nM1, nP1;
        ld_halo(t + 4, nA0, nB0);            // rows t+4, t+5
        ld_halo(t + 5, nA1, nB1);
        ld_sub (t - 27, nS0, nT0);           // (t+4)-31, (t+5)-31
        ld_sub (t - 26, nS1, nT1);
        ld_emit(t + 4, nM0, nP0);
        ld_emit(t + 5, nM1, nP1);

        process(qA0, qB0, qS0, qT0, qM0, qP0);
        process(qA1, qB1, qS1, qT1, qM1, qP1);

        qA0 = rA0; qB0 = rB0; qA1 = rA1; qB1 = rB1;
        qS0 = rS0; qT0 = rT0; qS1 = rS1; qT1 = rT1;
        qM0 = rM0; qP0 = rP0; qM1 = rP1 == rP1 ? rM1 : rM1; qP1 = rP1;  // keep simple moves
        qM1 = rM1;
        rA0 = nA0; rB0 = nB0; rA1 = nA1; rB1 = nB1;
        rS0 = nS0; rT0 = nT0; rS1 = nT1 == nT1 ? nS1 : nS1; rT1 = nT1;
        rS1 = nS1;
        rM0 = nM0; rP0 = nP0; rM1 = nM1; rP1 = nP1;
    }

    // ---- block reduction (8 waves) ----
#pragma unroll
    for (int off = 32; off > 0; off >>= 1) {
        bce_acc   += __shfl_down(bce_acc, off);
        inter_acc += __shfl_down(inter_acc, off);
        uni_acc   += __shfl_down(uni_acc, off);
    }
    if (lane == 0) {
        red[0][wv] = bce_acc;
        red[1][wv] = inter_acc;
        red[2][wv] = uni_acc;
    }
    __syncthreads();
    if (threadIdx.x == 0) {
        float bs = 0.f, is = 0.f, us = 0.f;
#pragma unroll
        for (int w = 0; w < 8; ++w) { bs += red[0][w]; is += red[1][w]; us += red[2][w]; }
        atomicAdd(&acc[0],      (double)bs);
        atomicAdd(&acc[1 + b],  (double)is);
        atomicAdd(&acc[65 + b], (double)us);
    }
}

__global__ void finalize_kernel(const double* __restrict__ acc, float* __restrict__ out) {
    const int b = threadIdx.x;   // one wave
    double inter = acc[1 + b];
    double uni   = acc[65 + b];
    double wiou  = 1.0 - (inter + 1.0) / (uni - inter + 1.0);
#pragma unroll
    for (int off = 32; off > 0; off >>= 1) wiou += __shfl_down(wiou, off);
    if (b == 0) {
        double wbce = acc[0] / (double)NPIX;
        out[0] = (float)(wbce + wiou / (double)BDIM);
    }
}

extern "C" void kernel_launch(void* const* d_in, const int* in_sizes, int n_in,
                              void* d_out, int out_size, void* d_ws, size_t ws_size,
                              hipStream_t stream) {
    const float* pred = (const float*)d_in[0];
    const float* mask = (const float*)d_in[1];
    float* out = (float*)d_out;
    double* acc = (double*)d_ws;

    zero_acc_kernel<<<1, 256, 0, stream>>>(acc);

    dim3 grid(BDIM, HDIM / TH);
    fused_kernel<<<grid, WDIM, 0, stream>>>(pred, mask, acc);

    finalize_kernel<<<1, 64, 0, stream>>>(acc, out);
}

// Round 3
// 170.251 us; speedup vs baseline: 1.0804x; 1.0804x over previous
//
#include <hip/hip_runtime.h>
#include <math.h>

#define BDIM 64
#define HDIM 512
#define WDIM 512
#define KW   31
#define PAD  15
#define INV_KK (1.0f / 961.0f)
#define TH   32                       // output rows per block (grid 64x16 = 1024 blocks)
#define NPIX ((size_t)BDIM * HDIM * WDIM)

// acc[0]: bce sum; acc[1..64]: inter[b]; acc[65..128]: union[b]
#define NACC 129

__global__ void zero_acc_kernel(double* acc) {
    int i = threadIdx.x;
    if (i < NACC) acc[i] = 0.0;
}

// ---- DPP helpers: VALU cross-lane (no LDS pipe) -------------------------
template<int CTRL, int RMASK>
__device__ __forceinline__ float dpp_add(float p) {
    int t = __builtin_amdgcn_update_dpp(0, __builtin_bit_cast(int, p),
                                        CTRL, RMASK, 0xf, true);
    return p + __builtin_bit_cast(float, t);
}

// inclusive prefix sum over 64 lanes
__device__ __forceinline__ float wave_iscan(float p) {
    p = dpp_add<0x111, 0xf>(p);   // row_shr:1
    p = dpp_add<0x112, 0xf>(p);   // row_shr:2
    p = dpp_add<0x114, 0xf>(p);   // row_shr:4
    p = dpp_add<0x118, 0xf>(p);   // row_shr:8
    p = dpp_add<0x142, 0xa>(p);   // row_bcast:15 -> rows 1,3
    p = dpp_add<0x143, 0xc>(p);   // row_bcast:31 -> rows 2,3
    return p;
}

// inclusive prefix valid through lane 31 (we only use lanes 0..29)
__device__ __forceinline__ float wave_iscan30(float p) {
    p = dpp_add<0x111, 0xf>(p);
    p = dpp_add<0x112, 0xf>(p);
    p = dpp_add<0x114, 0xf>(p);
    p = dpp_add<0x118, 0xf>(p);
    p = dpp_add<0x142, 0xa>(p);
    return p;
}

// lane i <- lane i-1 (lane 0 -> 0): inclusive->exclusive shift
__device__ __forceinline__ float wave_shr1(float p) {
    int t = __builtin_amdgcn_update_dpp(0, __builtin_bit_cast(int, p),
                                        0x138 /*WAVE_SHR1*/, 0xf, 0xf, true);
    return __builtin_bit_cast(float, t);
}

// Vertical-first separable box filter, ring-free.
// One block per (image, 32-row tile). 512 threads, 8 waves; each wave owns a
// 64-column strip. Per thread: running vertical 31-row sums (vsA, vsB) for its
// two halo columns, +row(t) - row(t-31) (the latter re-loaded: L2 hit).
// Horizontal 31-box via DPP prefix scan on the 32 emit rows only.
//
// Latency schedule: emit loop is a ping-pong 2-stage pipeline, unrolled by
// exactly 2 logical iterations with "#pragma unroll 1" on the hw loop so the
// scheduler CANNOT sink loads to uses (round-2 lesson: full unroll collapsed
// the prefetch distance). Loads overwrite the registers just consumed ->
// zero rotation moves; every load has ~1 body (~600 own cycles) + TLP of
// cover before use. Emit-phase prologue loads are issued before the warmup
// loop (~15 iterations of cover); warmup's final prefetches are handed to
// the emit loop as its first halo stages.
__global__ __launch_bounds__(512, 8)
void fused_kernel(const float* __restrict__ pred,
                  const float* __restrict__ mask,
                  double* __restrict__ acc) {
    __shared__ float red[3][8];

    const int b    = blockIdx.x;
    const int y0   = blockIdx.y * TH;
    const int x    = threadIdx.x;     // output column
    const int lane = x & 63;
    const int wv   = x >> 6;
    const int s    = wv * 64;         // strip start column

    const float* mbase = mask + (size_t)b * HDIM * WDIM;
    const float* pbase = pred + (size_t)b * HDIM * WDIM;

    const int acol = s - 15 + lane;             // halo column, pos 0..63
    const int bcol = s + 49 + lane;             // halo column, pos 64..93
    const bool a_ok = (acol >= 0) && (acol < WDIM);
    const bool b_ok = (lane < 30) && (bcol < WDIM);

    const int tstart = y0 - PAD;                // first row entering the vsum
    const int tend   = y0 + TH - 1 + PAD;       // last input row (62 total)
    const int smax   = (tstart > 0) ? tstart : 0;  // earliest valid subtracted row

    float vsA = 0.f, vsB = 0.f;                 // vertical 31-row column sums
    float bce_acc = 0.f, inter_acc = 0.f, uni_acc = 0.f;

    auto ld_halo = [&](int row, float& A, float& B) {
        A = 0.f; B = 0.f;
        if (row >= 0 && row < HDIM) {           // wave-uniform branch
            const float* rp = mbase + (size_t)row * WDIM;
            if (a_ok) A = rp[acol];             // exec-masked
            if (b_ok) B = rp[bcol];
        }
    };
    auto ld_sub = [&](int row, float& S, float& T) {
        S = 0.f; T = 0.f;
        if (row >= smax) {                      // wave-uniform branch
            const float* rp = mbase + (size_t)row * WDIM;
            if (a_ok) S = rp[acol];
            if (b_ok) T = rp[bcol];
        }
    };
    auto ld_emit = [&](int row, float& M, float& P) {
        M = 0.f; P = 0.f;
        if (row <= tend) {                      // prefetch-past-end guard
            const size_t off = (size_t)(row - PAD) * WDIM + x;
            M = mbase[off];
            P = pbase[off];
        }
    };

    auto process = [&](float A, float B, float S, float T, float M, float P) {
        vsA += A - S;                       // slide vertical window
        vsB += B - T;
        float pa = wave_iscan(vsA);         // prefix over positions 0..63
        float pb = wave_iscan30(vsB);       // prefix over positions 64..93
        const float atot = __builtin_bit_cast(float,
            __builtin_amdgcn_readlane(__builtin_bit_cast(int, pa), 63));
        const float v1 = __shfl(pa, (lane + 30) & 63);
        const float v2 = __shfl(pb, (lane + 30) & 63);   // = pb[lane-34] for lane>=34
        const float Phi = (lane <= 33) ? v1 : (atot + v2);
        const float Plo = wave_shr1(pa);
        const float hs  = Phi - Plo;        // full 31x31 box sum

        const float box  = hs * INV_KK;
        const float weit = 1.f + 5.f * fabsf(box - M);
        const float e1   = __expf(-fabsf(P));
        const float bce  = fmaxf(P, 0.f) - P * M + __logf(1.f + e1);
        const float rr   = __builtin_amdgcn_rcpf(1.f + e1);
        const float sp   = (P >= 0.f) ? rr : e1 * rr;    // sigmoid from e1
        bce_acc   += bce;
        inter_acc += sp * M * weit;
        uni_acc   += (sp + M) * weit;
    };

    const int t0 = y0 + PAD;                 // first emit-phase input row

    // ---- prologue: warmup stages + emit-phase prologue loads (early) ----
    float wA0, wB0, wA1, wB1;                // warmup stage: rows tstart, +1
    float xA0, xB0, xA1, xB1;                // warmup stage: rows tstart+2, +3
    ld_halo(tstart,     wA0, wB0);
    ld_halo(tstart + 1, wA1, wB1);
    ld_halo(tstart + 2, xA0, xB0);
    ld_halo(tstart + 3, xA1, xB1);

    float qS0, qT0, qS1, qT1, rS0, rT0, rS1, rT1;
    float qM0, qP0, qM1, qP1, rM0, rP0, rM1, rP1;
    ld_sub (t0 - 31, qS0, qT0);              // (t0)-31: masked to 0 unless y0>0
    ld_sub (t0 - 30, qS1, qT1);
    ld_sub (t0 - 29, rS0, rT0);
    ld_sub (t0 - 28, rS1, rT1);
    ld_emit(t0,      qM0, qP0);
    ld_emit(t0 + 1,  qM1, qP1);
    ld_emit(t0 + 2,  rM0, rP0);
    ld_emit(t0 + 3,  rM1, rP1);

    // ---- warmup: rows tstart .. y0+14 (30 rows, 15 iters), adds only ----
#pragma unroll 1
    for (int i = 0; i < 15; ++i) {
        const int t = tstart + 2 * i;
        float nA0, nB0, nA1, nB1;
        ld_halo(t + 4, nA0, nB0);
        ld_halo(t + 5, nA1, nB1);
        vsA += wA0 + wA1;
        vsB += wB0 + wB1;
        wA0 = xA0; wB0 = xB0; wA1 = xA1; wB1 = xB1;
        xA0 = nA0; xB0 = nB0; xA1 = nA1; xB1 = nB1;
    }
    // handoff: w = rows y0+15, y0+16 ; x = rows y0+17, y0+18 (already loaded)
    float qA0 = wA0, qB0 = wB0, qA1 = wA1, qB1 = wB1;
    float rA0 = xA0, rB0 = xB0, rA1 = xA1, rB1 = xB1;

    // ---- emit: rows y0+15 .. y0+46 (32 rows), ping-pong, 8 hw iters ----
#pragma unroll 1
    for (int k = 0; k < 8; ++k) {
        const int t = t0 + 4 * k;
        // stage q: rows t, t+1 (loaded one body ago), then reload for t+4, t+5
        process(qA0, qB0, qS0, qT0, qM0, qP0);
        process(qA1, qB1, qS1, qT1, qM1, qP1);
        ld_halo(t + 4, qA0, qB0);
        ld_halo(t + 5, qA1, qB1);
        ld_sub (t - 27, qS0, qT0);           // (t+4)-31
        ld_sub (t - 26, qS1, qT1);           // (t+5)-31
        ld_emit(t + 4, qM0, qP0);
        ld_emit(t + 5, qM1, qP1);
        // stage r: rows t+2, t+3, then reload for t+6, t+7
        process(rA0, rB0, rS0, rT0, rM0, rP0);
        process(rA1, rB1, rS1, rT1, rM1, rP1);
        ld_halo(t + 6, rA0, rB0);
        ld_halo(t + 7, rA1, rB1);
        ld_sub (t - 25, rS0, rT0);           // (t+6)-31
        ld_sub (t - 24, rS1, rT1);           // (t+7)-31
        ld_emit(t + 6, rM0, rP0);
        ld_emit(t + 7, rM1, rP1);
    }

    // ---- block reduction (8 waves) ----
#pragma unroll
    for (int off = 32; off > 0; off >>= 1) {
        bce_acc   += __shfl_down(bce_acc, off);
        inter_acc += __shfl_down(inter_acc, off);
        uni_acc   += __shfl_down(uni_acc, off);
    }
    if (lane == 0) {
        red[0][wv] = bce_acc;
        red[1][wv] = inter_acc;
        red[2][wv] = uni_acc;
    }
    __syncthreads();
    if (threadIdx.x == 0) {
        float bs = 0.f, is = 0.f, us = 0.f;
#pragma unroll
        for (int w = 0; w < 8; ++w) { bs += red[0][w]; is += red[1][w]; us += red[2][w]; }
        atomicAdd(&acc[0],      (double)bs);
        atomicAdd(&acc[1 + b],  (double)is);
        atomicAdd(&acc[65 + b], (double)us);
    }
}

__global__ void finalize_kernel(const double* __restrict__ acc, float* __restrict__ out) {
    const int b = threadIdx.x;   // one wave
    double inter = acc[1 + b];
    double uni   = acc[65 + b];
    double wiou  = 1.0 - (inter + 1.0) / (uni - inter + 1.0);
#pragma unroll
    for (int off = 32; off > 0; off >>= 1) wiou += __shfl_down(wiou, off);
    if (b == 0) {
        double wbce = acc[0] / (double)NPIX;
        out[0] = (float)(wbce + wiou / (double)BDIM);
    }
}

extern "C" void kernel_launch(void* const* d_in, const int* in_sizes, int n_in,
                              void* d_out, int out_size, void* d_ws, size_t ws_size,
                              hipStream_t stream) {
    const float* pred = (const float*)d_in[0];
    const float* mask = (const float*)d_in[1];
    float* out = (float*)d_out;
    double* acc = (double*)d_ws;

    zero_acc_kernel<<<1, 256, 0, stream>>>(acc);

    dim3 grid(BDIM, HDIM / TH);
    fused_kernel<<<grid, WDIM, 0, stream>>>(pred, mask, acc);

    finalize_kernel<<<1, 64, 0, stream>>>(acc, out);
}